// Round 8
// baseline (44.643 us; speedup 1.0000x reference)
//
#include <hip/hip_runtime.h>
#include <hip/hip_bf16.h>

typedef __attribute__((ext_vector_type(8))) short short8;
typedef __attribute__((ext_vector_type(4))) float f32x4;

#define MFMA(a, b, c) __builtin_amdgcn_mfma_f32_16x16x32_bf16((a), (b), (c), 0, 0, 0)

// packed pair: low 16 = bf16(a), high 16 = bf16(b) -> v_cvt_pk_bf16_f32
__device__ __forceinline__ unsigned int f2bf2(float a, float b) {
  __hip_bfloat162 h2 = __float22bfloat162_rn(make_float2(a, b));
  union { __hip_bfloat162 h; unsigned int u; } cv; cv.h = h2;
  return cv.u;
}

// ---------------------------------------------------------------------------
// k0: W -> W3t bf16 in FRAG-LINEAR layout: 16B chunk index
//   j = (kstep*12 + ct)*64 + lane,  lane=(g*16+q)
// holding W^T[n=16ct'+q][k=32*kstep+8g .. +7]  (ct': Q ct 0-3, K 4-7, V 8-11)
// so fused's B-frag ds_read_b128 is lane-unit-stride (conflict-free).
// ---------------------------------------------------------------------------
__global__ void wconv_kernel(const float* __restrict__ Wq, const float* __restrict__ Wk,
                             const float* __restrict__ Wv, unsigned short* __restrict__ W3t) {
  int j = blockIdx.x * 128 + threadIdx.x;  // 0..9215 (uint4 chunks)
  int s = j / 768;
  int r = j - s * 768;
  int ct = r >> 6, l = r & 63, g = l >> 4, q = l & 15;
  const float* src = (ct < 4) ? Wq : ((ct < 8) ? Wk : Wv);
  int col = 16 * (ct & 3) + q;
  int k = 32 * s + 8 * g;
  float e[8];
#pragma unroll
  for (int i = 0; i < 8; ++i) e[i] = src[(k + i) * 64 + col];
  uint4 u;
  u.x = f2bf2(e[0], e[1]); u.y = f2bf2(e[2], e[3]);
  u.z = f2bf2(e[4], e[5]); u.w = f2bf2(e[6], e[7]);
  *(uint4*)&W3t[j * 8] = u;
}

// ---------------------------------------------------------------------------
// Fused per-batch kernel. 1024 threads = 16 waves (4/SIMD), 1 block/CU.
// Dynamic LDS 147456 B (73728 ush):
//   proj-phase: Wf frag-linear, whole W (9216 x 16B chunks)
//   attn-phase (overlays Wf): Ql [256][72] @0 | Kl @18432 | Vl [64][264] @36864
//                             Pb 16 x [16][40] @53760 (ends 64000 ush)
// Proj split (LDS-BW lever): wave w -> row-pair a=w>>1 (rows 32a..32a+31),
//   col-half h=w&1 (col-tiles 6h..6h+5). Each wave reads only HALF of W from
//   LDS (6 B-frags/step); each x row is read by 2 adjacent waves (cache-hit).
//   NO main-loop barriers; BK=32 free-run; 1-step x prefetch.
// Attn: swapped QK^T (scores lane-local per q-row), online softmax, tile t=w;
//   per-row factors redistributed to accumulator rows via __shfl.
// ---------------------------------------------------------------------------
__global__ __launch_bounds__(1024) void fused_kernel(
    const float* __restrict__ x, const unsigned short* __restrict__ W3t,
    float* __restrict__ out) {
  extern __shared__ unsigned short sm[];
  unsigned short* Ql = sm;
  unsigned short* Kl = sm + 18432;
  unsigned short* Vl = sm + 36864;

  const int tid = threadIdx.x;  // 0..1023
  const int w = tid >> 6, lane = tid & 63, g = lane >> 4, q = lane & 15;
  const int b = blockIdx.x;
  const float* xb = x + (long)b * 98304;

  // ---- stage whole W into LDS (frag-linear; coalesced; conflict-free) ----
#pragma unroll
  for (int i = 0; i < 9; ++i) {
    int idx = tid + i * 1024;  // uint4 chunk index
    *(uint4*)&sm[idx * 8] = *(const uint4*)&W3t[idx * 8];
  }

  const int a = w >> 1, h = w & 1;  // row-pair / col-half split
  f32x4 acc[2][6];
  const f32x4 zf = {0.f, 0.f, 0.f, 0.f};
#pragma unroll
  for (int i = 0; i < 2; ++i)
#pragma unroll
    for (int j = 0; j < 6; ++j) acc[i][j] = zf;

  // x A-frag sources: lane (q,g) owns rows 32a+q and 32a+16+q, k-chunk 8g
  const float* xrA = xb + (32 * a + q) * 384 + 8 * g;
  const float* xrB = xrA + 16 * 384;
  float4 x0 = *(const float4*)&xrA[0];
  float4 x1 = *(const float4*)&xrA[4];
  float4 x2 = *(const float4*)&xrB[0];
  float4 x3 = *(const float4*)&xrB[4];

  __syncthreads();  // Wf staged

  // ---- proj main loop: 12 x BK=32, free-running, no barriers ----
#pragma unroll
  for (int ks = 0; ks < 12; ++ks) {
    float4 n0, n1, n2, n3;
    if (ks < 11) {
      n0 = *(const float4*)&xrA[32 * (ks + 1)];
      n1 = *(const float4*)&xrA[32 * (ks + 1) + 4];
      n2 = *(const float4*)&xrB[32 * (ks + 1)];
      n3 = *(const float4*)&xrB[32 * (ks + 1) + 4];
    }
    uint4 auA, auB;
    auA.x = f2bf2(x0.x, x0.y); auA.y = f2bf2(x0.z, x0.w);
    auA.z = f2bf2(x1.x, x1.y); auA.w = f2bf2(x1.z, x1.w);
    auB.x = f2bf2(x2.x, x2.y); auB.y = f2bf2(x2.z, x2.w);
    auB.z = f2bf2(x3.x, x3.y); auB.w = f2bf2(x3.z, x3.w);
    union { uint4 u; short8 s8; } avA, avB;
    avA.u = auA; avB.u = auB;
    // B-frags: only this wave's col-half (6 of 12 tiles)
    const unsigned short* wbase = sm + ks * 6144 + h * 3072 + lane * 8;
#pragma unroll
    for (int ct = 0; ct < 6; ++ct) {
      short8 bfr = *(const short8*)&wbase[ct * 512];
      acc[0][ct] = MFMA(avA.s8, bfr, acc[0][ct]);
      acc[1][ct] = MFMA(avB.s8, bfr, acc[1][ct]);
    }
    if (ks < 11) { x0 = n0; x1 = n1; x2 = n2; x3 = n3; }  // renamed (unrolled)
  }
  __syncthreads();  // all waves done reading Wf; safe to overlay

  // ---- proj epilogue: QKV -> LDS (D layout: col=lane&15, row=4g+reg) ----
#pragma unroll
  for (int rt = 0; rt < 2; ++rt) {
    const int mb = 32 * a + 16 * rt + 4 * g;  // within-batch row base
#pragma unroll
    for (int ct = 0; ct < 6; ++ct) {
      const int cti = 6 * h + ct;  // global col-tile 0..11
      int c = 16 * cti + q;
      unsigned int p01 = f2bf2(acc[rt][ct][0], acc[rt][ct][1]);
      unsigned int p23 = f2bf2(acc[rt][ct][2], acc[rt][ct][3]);
      unsigned short h0 = (unsigned short)p01, h1 = (unsigned short)(p01 >> 16);
      unsigned short h2 = (unsigned short)p23, h3 = (unsigned short)(p23 >> 16);
      if (cti < 4) {
        Ql[(mb + 0) * 72 + c] = h0; Ql[(mb + 1) * 72 + c] = h1;
        Ql[(mb + 2) * 72 + c] = h2; Ql[(mb + 3) * 72 + c] = h3;
      } else if (cti < 8) {
        int cc = c - 64;
        Kl[(mb + 0) * 72 + cc] = h0; Kl[(mb + 1) * 72 + cc] = h1;
        Kl[(mb + 2) * 72 + cc] = h2; Kl[(mb + 3) * 72 + cc] = h3;
      } else {
        int hh = c - 128;
        uint2 pk; pk.x = p01; pk.y = p23;
        *(uint2*)&Vl[hh * 264 + mb] = pk;  // V^T[h][tok..tok+3]
      }
    }
  }
  __syncthreads();

  // ---- attention: wave w owns row-tile t = w; swapped QK^T + online SM ----
  unsigned short* Pb = sm + 53760 + w * 640;  // per-wave [16][40] P buffer
  const float SCL = 0.125f * 1.4426950408889634f;  // H^-0.5 * log2(e)
  const int t = w;

  // Q as B-operand: lane (q,g) holds Q[16t+q][8g..8g+7]
  short8 aq0 = *(const short8*)&Ql[(16 * t + q) * 72 + g * 8];
  short8 aq1 = *(const short8*)&Ql[(16 * t + q) * 72 + 32 + g * 8];

  f32x4 o[4];
#pragma unroll
  for (int ct = 0; ct < 4; ++ct) o[ct] = zf;
  float m = -1e30f;   // running max for q-row 16t+q
  float lsum = 0.f;   // per-lane partial row-sum for q-row 16t+q

  const int KS = (t >> 1) + 1;  // runtime trip count, wave-uniform
  for (int ks = 0; ks < KS; ++ks) {
    const int j0 = 2 * ks, j1 = 2 * ks + 1;
    const bool has1 = (j1 <= t);
    // K as A-operand: D[row=4g+jr][col=q] = S[K-token 16j+4g+jr][Q-row 16t+q]
    short8 ka0 = *(const short8*)&Kl[(16 * j0 + q) * 72 + g * 8];
    short8 ka1 = *(const short8*)&Kl[(16 * j0 + q) * 72 + 32 + g * 8];
    f32x4 s0 = MFMA(ka0, aq0, zf);
    s0 = MFMA(ka1, aq1, s0);
    f32x4 s1 = zf;
    if (has1) {
      short8 kb0 = *(const short8*)&Kl[(16 * j1 + q) * 72 + g * 8];
      short8 kb1 = *(const short8*)&Kl[(16 * j1 + q) * 72 + 32 + g * 8];
      s1 = MFMA(kb0, aq0, zf);
      s1 = MFMA(kb1, aq1, s1);
    }
    float v[8];
#pragma unroll
    for (int jr = 0; jr < 4; ++jr) {
      float aa = s0[jr] * SCL;
      if (j0 == t && 4 * g + jr > q) aa = -1e30f;  // causal (diag tile)
      v[jr] = aa;
      float c = has1 ? s1[jr] * SCL : -1e30f;
      if (has1 && j1 == t && 4 * g + jr > q) c = -1e30f;
      v[4 + jr] = c;
    }
    float mloc = fmaxf(fmaxf(fmaxf(v[0], v[1]), fmaxf(v[2], v[3])),
                       fmaxf(fmaxf(v[4], v[5]), fmaxf(v[6], v[7])));
    mloc = fmaxf(mloc, __shfl_xor(mloc, 16));
    mloc = fmaxf(mloc, __shfl_xor(mloc, 32));
    float mnew = fmaxf(m, mloc);
    float f = exp2f(m - mnew);  // rescale factor for q-row q (this lane's row)
    m = mnew;
    float p[8];
    float ls = 0.f;
#pragma unroll
    for (int i = 0; i < 8; ++i) { p[i] = exp2f(v[i] - mnew); ls += p[i]; }
    lsum = lsum * f + ls;
    // o[ct][jr] accumulates Q-row 4g+jr -> fetch THAT row's factor (lane 4g+jr)
#pragma unroll
    for (int jr = 0; jr < 4; ++jr) {
      float fr = __shfl(f, 4 * g + jr);
      o[0][jr] *= fr; o[1][jr] *= fr; o[2][jr] *= fr; o[3][jr] *= fr;
    }
    // P store (row q, cols 4g..4g+3 of each 16-tile) then transposed read
    uint2 pa; pa.x = f2bf2(p[0], p[1]); pa.y = f2bf2(p[2], p[3]);
    *(uint2*)&Pb[q * 40 + 4 * g] = pa;
    uint2 pc; pc.x = f2bf2(p[4], p[5]); pc.y = f2bf2(p[6], p[7]);
    *(uint2*)&Pb[q * 40 + 16 + 4 * g] = pc;
    short8 ap = *(const short8*)&Pb[q * 40 + g * 8];
#pragma unroll
    for (int ct = 0; ct < 4; ++ct) {
      short8 bv = *(const short8*)&Vl[(16 * ct + q) * 264 + ks * 32 + g * 8];
      o[ct] = MFMA(ap, bv, o[ct]);
    }
  }

  // final row-sum: fold g-partials (row q), then fetch row 4g+jr's sum
  lsum += __shfl_xor(lsum, 16);
  lsum += __shfl_xor(lsum, 32);
  float linv[4];
#pragma unroll
  for (int jr = 0; jr < 4; ++jr) linv[jr] = 1.0f / __shfl(lsum, 4 * g + jr);

  const long rowbase = (long)b * 256 + 16 * t;
#pragma unroll
  for (int jr = 0; jr < 4; ++jr) {
#pragma unroll
    for (int ct = 0; ct < 4; ++ct) {
      out[(rowbase + 4 * g + jr) * 64 + 16 * ct + q] = o[ct][jr] * linv[jr];
    }
  }
}

// ---------------------------------------------------------------------------
extern "C" void kernel_launch(void* const* d_in, const int* in_sizes, int n_in,
                              void* d_out, int out_size, void* d_ws, size_t ws_size,
                              hipStream_t stream) {
  const float* x  = (const float*)d_in[0];
  const float* Wq = (const float*)d_in[1];
  const float* Wk = (const float*)d_in[2];
  const float* Wv = (const float*)d_in[3];
  float* out = (float*)d_out;

  unsigned short* W3t = (unsigned short*)d_ws;  // 147,456 B

  hipFuncSetAttribute((const void*)fused_kernel,
                      hipFuncAttributeMaxDynamicSharedMemorySize, 147456);

  wconv_kernel<<<72, 128, 0, stream>>>(Wq, Wk, Wv, W3t);
  fused_kernel<<<256, 1024, 147456, stream>>>(x, W3t, out);
}

// Round 9
// 37.907 us; speedup vs baseline: 1.1777x; 1.1777x over previous
//
#include <hip/hip_runtime.h>
#include <hip/hip_bf16.h>

typedef __attribute__((ext_vector_type(8))) short short8;
typedef __attribute__((ext_vector_type(4))) float f32x4;

#define MFMA(a, b, c) __builtin_amdgcn_mfma_f32_16x16x32_bf16((a), (b), (c), 0, 0, 0)

// packed pair: low 16 = bf16(a), high 16 = bf16(b) -> v_cvt_pk_bf16_f32
__device__ __forceinline__ unsigned int f2bf2(float a, float b) {
  __hip_bfloat162 h2 = __float22bfloat162_rn(make_float2(a, b));
  union { __hip_bfloat162 h; unsigned int u; } cv; cv.h = h2;
  return cv.u;
}

__device__ __forceinline__ unsigned short f2bf(float f) {
  union { float f; unsigned int u; } v; v.f = f;
  unsigned int u = v.u;
  unsigned int r = u + 0x7FFFu + ((u >> 16) & 1u);
  return (unsigned short)(r >> 16);
}

// ---------------------------------------------------------------------------
// k0: W -> W3t bf16 in FRAG-LINEAR layout: 16B chunk index
//   j = (kstep*12 + ct)*64 + lane,  lane=(g*16+q)
// holding W^T[n=16ct'+q][k=32*kstep+8g .. +7]  (ct': Q ct 0-3, K 4-7, V 8-11)
// so fused's B-frag ds_read_b128 is lane-unit-stride (conflict-free).
// ---------------------------------------------------------------------------
__global__ void wconv_kernel(const float* __restrict__ Wq, const float* __restrict__ Wk,
                             const float* __restrict__ Wv, unsigned short* __restrict__ W3t) {
  int j = blockIdx.x * 128 + threadIdx.x;  // 0..9215 (uint4 chunks)
  int s = j / 768;
  int r = j - s * 768;
  int ct = r >> 6, l = r & 63, g = l >> 4, q = l & 15;
  const float* src = (ct < 4) ? Wq : ((ct < 8) ? Wk : Wv);
  int col = 16 * (ct & 3) + q;
  int k = 32 * s + 8 * g;
  float e[8];
#pragma unroll
  for (int i = 0; i < 8; ++i) e[i] = src[(k + i) * 64 + col];
  uint4 u;
  u.x = f2bf2(e[0], e[1]); u.y = f2bf2(e[2], e[3]);
  u.z = f2bf2(e[4], e[5]); u.w = f2bf2(e[6], e[7]);
  *(uint4*)&W3t[j * 8] = u;
}

// ---------------------------------------------------------------------------
// Fused per-batch kernel. 1024 threads = 16 waves (4/SIMD), 1 block/CU.
// Dynamic LDS 147456 B (73728 ush):
//   proj-phase: Wf frag-linear, whole W (9216 x 16B chunks)
//   attn-phase (overlays Wf): Ql [256][72] @0 | Kl @18432 | Vl [64][264] @36864
//                             Pb 16 x [16][40] @53760 (ends 64000 ush)
// Proj (R6 structure + DEPTH-4 x prefetch): wave w owns rows 16w..16w+15,
//   reads full W from LDS (12 B-frags/step). 8 float4 x-loads in flight
//   (4 steps ahead) -> no wave blocks on x; LDS/MFMA stream runs free.
//   NO main-loop barriers.
// Attn: swapped QK^T (scores lane-local per q-row), online softmax, tile t=w;
//   per-row factors redistributed to accumulator rows via __shfl.
// ---------------------------------------------------------------------------
__global__ __launch_bounds__(1024) void fused_kernel(
    const float* __restrict__ x, const unsigned short* __restrict__ W3t,
    float* __restrict__ out) {
  extern __shared__ unsigned short sm[];
  unsigned short* Ql = sm;
  unsigned short* Kl = sm + 18432;
  unsigned short* Vl = sm + 36864;

  const int tid = threadIdx.x;  // 0..1023
  const int w = tid >> 6, lane = tid & 63, g = lane >> 4, q = lane & 15;
  const int b = blockIdx.x;
  const float* xb = x + (long)b * 98304;

  // ---- stage whole W into LDS (frag-linear; coalesced; conflict-free) ----
#pragma unroll
  for (int i = 0; i < 9; ++i) {
    int idx = tid + i * 1024;  // uint4 chunk index
    *(uint4*)&sm[idx * 8] = *(const uint4*)&W3t[idx * 8];
  }

  f32x4 acc[12];
  const f32x4 zf = {0.f, 0.f, 0.f, 0.f};
#pragma unroll
  for (int j = 0; j < 12; ++j) acc[j] = zf;

  // x A-frag source: lane (q,g) owns row 16w+q, k-chunk 8g (+32*ks)
  // DEPTH-4 prefetch: slots 0..3 hold steps ks..ks+3 (compile-time rotation)
  const float* xrow = xb + (16 * w + q) * 384 + 8 * g;
  float4 xa[4], xc[4];
#pragma unroll
  for (int i = 0; i < 4; ++i) {
    xa[i] = *(const float4*)&xrow[32 * i];
    xc[i] = *(const float4*)&xrow[32 * i + 4];
  }

  __syncthreads();  // Wf staged (x prologue loads drain here too; one-time)

  // ---- proj main loop: 12 x BK=32, free-running, no barriers ----
#pragma unroll
  for (int ks = 0; ks < 12; ++ks) {
    const int cur = ks & 3;  // constant after unroll -> stays in VGPRs
    uint4 au;
    au.x = f2bf2(xa[cur].x, xa[cur].y); au.y = f2bf2(xa[cur].z, xa[cur].w);
    au.z = f2bf2(xc[cur].x, xc[cur].y); au.w = f2bf2(xc[cur].z, xc[cur].w);
    union { uint4 u; short8 s8; } av; av.u = au;
    // refill slot with step ks+4 (slot regs just consumed)
    if (ks < 8) {
      xa[cur] = *(const float4*)&xrow[32 * (ks + 4)];
      xc[cur] = *(const float4*)&xrow[32 * (ks + 4) + 4];
    }
    const unsigned short* wbase = sm + ks * 6144 + lane * 8;
#pragma unroll
    for (int ct = 0; ct < 12; ++ct) {
      short8 bfr = *(const short8*)&wbase[ct * 512];
      acc[ct] = MFMA(av.s8, bfr, acc[ct]);
    }
  }
  __syncthreads();  // all waves done reading Wf; safe to overlay

  // ---- proj epilogue: QKV -> LDS (D layout: col=lane&15, row=4g+reg) ----
  {
    const int mb = 16 * w + 4 * g;  // within-batch row base
#pragma unroll
    for (int ct = 0; ct < 12; ++ct) {
      int c = 16 * ct + q;
      unsigned int p01 = f2bf2(acc[ct][0], acc[ct][1]);
      unsigned int p23 = f2bf2(acc[ct][2], acc[ct][3]);
      unsigned short h0 = (unsigned short)p01, h1 = (unsigned short)(p01 >> 16);
      unsigned short h2 = (unsigned short)p23, h3 = (unsigned short)(p23 >> 16);
      if (ct < 4) {
        Ql[(mb + 0) * 72 + c] = h0; Ql[(mb + 1) * 72 + c] = h1;
        Ql[(mb + 2) * 72 + c] = h2; Ql[(mb + 3) * 72 + c] = h3;
      } else if (ct < 8) {
        int cc = c - 64;
        Kl[(mb + 0) * 72 + cc] = h0; Kl[(mb + 1) * 72 + cc] = h1;
        Kl[(mb + 2) * 72 + cc] = h2; Kl[(mb + 3) * 72 + cc] = h3;
      } else {
        int hh = c - 128;
        uint2 pk; pk.x = p01; pk.y = p23;
        *(uint2*)&Vl[hh * 264 + mb] = pk;  // V^T[h][tok..tok+3]
      }
    }
  }
  __syncthreads();

  // ---- attention: wave w owns row-tile t = w; swapped QK^T + online SM ----
  unsigned short* Pb = sm + 53760 + w * 640;  // per-wave [16][40] P buffer
  const float SCL = 0.125f * 1.4426950408889634f;  // H^-0.5 * log2(e)
  const int t = w;

  // Q as B-operand: lane (q,g) holds Q[16t+q][8g..8g+7]
  short8 aq0 = *(const short8*)&Ql[(16 * t + q) * 72 + g * 8];
  short8 aq1 = *(const short8*)&Ql[(16 * t + q) * 72 + 32 + g * 8];

  f32x4 o[4];
#pragma unroll
  for (int ct = 0; ct < 4; ++ct) o[ct] = zf;
  float m = -1e30f;   // running max for q-row 16t+q
  float lsum = 0.f;   // per-lane partial row-sum for q-row 16t+q

  const int KS = (t >> 1) + 1;  // runtime trip count, wave-uniform
  for (int ks = 0; ks < KS; ++ks) {
    const int j0 = 2 * ks, j1 = 2 * ks + 1;
    const bool has1 = (j1 <= t);
    // K as A-operand: D[row=4g+jr][col=q] = S[K-token 16j+4g+jr][Q-row 16t+q]
    short8 ka0 = *(const short8*)&Kl[(16 * j0 + q) * 72 + g * 8];
    short8 ka1 = *(const short8*)&Kl[(16 * j0 + q) * 72 + 32 + g * 8];
    f32x4 s0 = MFMA(ka0, aq0, zf);
    s0 = MFMA(ka1, aq1, s0);
    f32x4 s1 = zf;
    if (has1) {
      short8 kb0 = *(const short8*)&Kl[(16 * j1 + q) * 72 + g * 8];
      short8 kb1 = *(const short8*)&Kl[(16 * j1 + q) * 72 + 32 + g * 8];
      s1 = MFMA(kb0, aq0, zf);
      s1 = MFMA(kb1, aq1, s1);
    }
    float v[8];
#pragma unroll
    for (int jr = 0; jr < 4; ++jr) {
      float aa = s0[jr] * SCL;
      if (j0 == t && 4 * g + jr > q) aa = -1e30f;  // causal (diag tile)
      v[jr] = aa;
      float c = has1 ? s1[jr] * SCL : -1e30f;
      if (has1 && j1 == t && 4 * g + jr > q) c = -1e30f;
      v[4 + jr] = c;
    }
    float mloc = fmaxf(fmaxf(fmaxf(v[0], v[1]), fmaxf(v[2], v[3])),
                       fmaxf(fmaxf(v[4], v[5]), fmaxf(v[6], v[7])));
    mloc = fmaxf(mloc, __shfl_xor(mloc, 16));
    mloc = fmaxf(mloc, __shfl_xor(mloc, 32));
    float mnew = fmaxf(m, mloc);
    float f = exp2f(m - mnew);  // rescale factor for q-row q (this lane's row)
    m = mnew;
    float p[8];
    float ls = 0.f;
#pragma unroll
    for (int i = 0; i < 8; ++i) { p[i] = exp2f(v[i] - mnew); ls += p[i]; }
    lsum = lsum * f + ls;
    // o[ct][jr] accumulates Q-row 4g+jr -> fetch THAT row's factor (lane 4g+jr)
#pragma unroll
    for (int jr = 0; jr < 4; ++jr) {
      float fr = __shfl(f, 4 * g + jr);
      o[0][jr] *= fr; o[1][jr] *= fr; o[2][jr] *= fr; o[3][jr] *= fr;
    }
    // P store (row q, cols 4g..4g+3 of each 16-tile) then transposed read
    uint2 pa; pa.x = f2bf2(p[0], p[1]); pa.y = f2bf2(p[2], p[3]);
    *(uint2*)&Pb[q * 40 + 4 * g] = pa;
    uint2 pc; pc.x = f2bf2(p[4], p[5]); pc.y = f2bf2(p[6], p[7]);
    *(uint2*)&Pb[q * 40 + 16 + 4 * g] = pc;
    short8 ap = *(const short8*)&Pb[q * 40 + g * 8];
#pragma unroll
    for (int ct = 0; ct < 4; ++ct) {
      short8 bv = *(const short8*)&Vl[(16 * ct + q) * 264 + ks * 32 + g * 8];
      o[ct] = MFMA(ap, bv, o[ct]);
    }
  }

  // final row-sum: fold g-partials (row q), then fetch row 4g+jr's sum
  lsum += __shfl_xor(lsum, 16);
  lsum += __shfl_xor(lsum, 32);
  float linv[4];
#pragma unroll
  for (int jr = 0; jr < 4; ++jr) linv[jr] = 1.0f / __shfl(lsum, 4 * g + jr);

  const long rowbase = (long)b * 256 + 16 * t;
#pragma unroll
  for (int jr = 0; jr < 4; ++jr) {
#pragma unroll
    for (int ct = 0; ct < 4; ++ct) {
      out[(rowbase + 4 * g + jr) * 64 + 16 * ct + q] = o[ct][jr] * linv[jr];
    }
  }
}

// ---------------------------------------------------------------------------
extern "C" void kernel_launch(void* const* d_in, const int* in_sizes, int n_in,
                              void* d_out, int out_size, void* d_ws, size_t ws_size,
                              hipStream_t stream) {
  const float* x  = (const float*)d_in[0];
  const float* Wq = (const float*)d_in[1];
  const float* Wk = (const float*)d_in[2];
  const float* Wv = (const float*)d_in[3];
  float* out = (float*)d_out;

  unsigned short* W3t = (unsigned short*)d_ws;  // 147,456 B

  hipFuncSetAttribute((const void*)fused_kernel,
                      hipFuncAttributeMaxDynamicSharedMemorySize, 147456);

  wconv_kernel<<<72, 128, 0, stream>>>(Wq, Wk, Wv, W3t);
  fused_kernel<<<256, 1024, 147456, stream>>>(x, W3t, out);
}